// Round 19
// baseline (123.220 us; speedup 1.0000x reference)
//
#include <hip/hip_runtime.h>
#include <math.h>

#define NN 100000
#define NE 1600000
#define F_IN 64
#define HID 16
#define OUTF 32
#define BKT_SHIFT 6
#define BKT_NODES 64
#define NBKT 1563               // ceil(NN/64)
#define SRCM 0x1FFFF
#define CAP_REG 2048            // fixed region per bucket (mean 1024, sd 32)
#define CAP_LDS 1184            // fast-path LDS sort capacity (5 sigma; legacy covers rest)
#define PBLK3 200
#define EPB3 8000               // 200*8000 = 1.6M exact
#define CHUNK 2000              // 4 chunks per block
#define NCHK 4
#define OVF_MAX 4096
#define PROJ_BLKS 98            // 98*1024 = 100352 >= NN

__device__ __forceinline__ unsigned bf16r(float f) {
    unsigned u = __float_as_uint(f);
    return (u + 0x7FFFu + ((u >> 16) & 1u)) >> 16;
}
__device__ __forceinline__ float bfa(unsigned p) { return __uint_as_float(p << 16); }
__device__ __forceinline__ float bfd(unsigned p) { return __uint_as_float(p & 0xFFFF0000u); }
__device__ __forceinline__ float bfh(unsigned short v) { return __uint_as_float(((unsigned)v) << 16); }

__device__ __forceinline__ void acc8(uint4 hv, float u, float* s0, float* s1) {
    unsigned w[4] = {hv.x, hv.y, hv.z, hv.w};
#pragma unroll
    for (int q = 0; q < 4; ++q) {
        float lo = __uint_as_float(w[q] << 16);
        float hi = __uint_as_float(w[q] & 0xFFFF0000u);
        s0[2 * q]     += lo; s1[2 * q]     = fmaf(u, lo, s1[2 * q]);
        s0[2 * q + 1] += hi; s1[2 * q + 1] = fmaf(u, hi, s1[2 * q + 1]);
    }
}
__device__ __forceinline__ void acc4(uint4 ap, float u, float* a) {
    unsigned w[4] = {ap.x, ap.y, ap.z, ap.w};
#pragma unroll
    for (int q = 0; q < 4; ++q)
        a[q] += fmaf(u, bfd(w[q]), bfa(w[q]));
}

// ---- zero gcur/novf (must precede fused kernel) ----
__global__ __launch_bounds__(256) void zeroG_kernel(int* __restrict__ gcur,
                                                    int* __restrict__ novf) {
    int t = blockIdx.x * 256 + threadIdx.x;
    if (t < NBKT) gcur[t] = 0;
    if (t == NBKT) novf[0] = 0;
}

// ---- FUSED: blocks 0..199 = partition v3; blocks 200..297 = layer-1 projection ----
__global__ __launch_bounds__(1024) void fusedPP_kernel(const int* __restrict__ ei,
                                                       const float* __restrict__ ea,
                                                       int* __restrict__ gcur,
                                                       int* __restrict__ novf,
                                                       int4* __restrict__ ovf,
                                                       int2* __restrict__ bkt,
                                                       const float* __restrict__ x,
                                                       const float* __restrict__ W1,
                                                       const float* __restrict__ root1,
                                                       const float* __restrict__ bias1,
                                                       unsigned* __restrict__ ab1p,
                                                       float* __restrict__ r1) {
    __shared__ int gpos[NBKT];
    __shared__ int segc[NBKT];
    __shared__ int pw[16];
    __shared__ int2 sbuf[CHUNK];    // 16 KB
    int t = threadIdx.x, blk = blockIdx.x;

    if (blk >= PBLK3) {
        // ======== projection path (blocks 200..297, 1024 threads = 1024 nodes) ========
        float* w  = (float*)sbuf;            // 2048 floats (8 KB of sbuf)
        float* wr = (float*)gpos;            // reuse gpos+segc: 1563+1563 ints >= 1024 floats? gpos is 1563 ints = fits 1024 floats
        __shared__ float bb[HID];
        for (int i = t; i < 2 * F_IN * HID; i += 1024) w[i] = W1[i];
        for (int i = t; i < F_IN * HID; i += 1024) wr[i] = root1[i];
        if (t < HID) bb[t] = bias1[t];
        __syncthreads();
        int n = (blk - PBLK3) * 1024 + t;
        if (n >= NN) return;
        float accA[HID], accB[HID], accR[HID];
#pragma unroll
        for (int o = 0; o < HID; ++o) { accA[o] = 0.f; accB[o] = 0.f; accR[o] = bb[o]; }
        const float4* xr4 = (const float4*)(x + (size_t)n * F_IN);
        for (int f4 = 0; f4 < F_IN / 4; ++f4) {
            float4 xv4 = xr4[f4];
            float xs[4] = {xv4.x, xv4.y, xv4.z, xv4.w};
#pragma unroll
            for (int q = 0; q < 4; ++q) {
                int f = f4 * 4 + q;
                float xv = xs[q];
                const float* w0 = &w[f * HID];
                const float* w1 = &w[F_IN * HID + f * HID];
                const float* w2 = &wr[f * HID];
#pragma unroll
                for (int o = 0; o < HID; ++o) {
                    accA[o] = fmaf(xv, w0[o], accA[o]);
                    accB[o] = fmaf(xv, w1[o], accB[o]);
                    accR[o] = fmaf(xv, w2[o], accR[o]);
                }
            }
        }
        unsigned* ar = ab1p + (size_t)n * HID;
        float* rr = r1 + (size_t)n * HID;
#pragma unroll
        for (int o = 0; o < HID; ++o) {
            ar[o] = bf16r(accA[o]) | (bf16r(accB[o] - accA[o]) << 16);
            rr[o] = accR[o];
        }
        return;
    }

    // ======== partition path (blocks 0..199) ========
    for (int i = t; i < NBKT; i += 1024) gpos[i] = 0;
    __syncthreads();
    int beg = blk * EPB3;
    for (int i = t; i < EPB3 / 4; i += 1024) {
        int4 d4 = *(const int4*)(ei + NE + beg + 4 * i);
        atomicAdd(&gpos[d4.x >> BKT_SHIFT], 1);
        atomicAdd(&gpos[d4.y >> BKT_SHIFT], 1);
        atomicAdd(&gpos[d4.z >> BKT_SHIFT], 1);
        atomicAdd(&gpos[d4.w >> BKT_SHIFT], 1);
    }
    __syncthreads();
    int rot = (blk * 397) % NBKT;
    for (int k = t; k < NBKT; k += 1024) {
        int i = k + rot; if (i >= NBKT) i -= NBKT;
        int c = gpos[i];
        gpos[i] = c ? atomicAdd(&gcur[i], c) : 0;
    }
    __syncthreads();
    for (int c = 0; c < NCHK; ++c) {
        int cbeg = beg + c * CHUNK;
        for (int i = t; i < NBKT; i += 1024) segc[i] = 0;
        __syncthreads();
        for (int i = t; i < CHUNK / 4; i += 1024) {
            int4 d4 = *(const int4*)(ei + NE + cbeg + 4 * i);
            atomicAdd(&segc[d4.x >> BKT_SHIFT], 1);
            atomicAdd(&segc[d4.y >> BKT_SHIFT], 1);
            atomicAdd(&segc[d4.z >> BKT_SHIFT], 1);
            atomicAdd(&segc[d4.w >> BKT_SHIFT], 1);
        }
        __syncthreads();
        int i0 = 2 * t, i1 = 2 * t + 1;
        int v0 = (i0 < NBKT) ? segc[i0] : 0;
        int v1 = (i1 < NBKT) ? segc[i1] : 0;
        int ts = v0 + v1;
        int lane = t & 63, wid = t >> 6;
        int sc = ts;
#pragma unroll
        for (int off = 1; off < 64; off <<= 1) {
            int o = __shfl_up(sc, off, 64);
            if (lane >= off) sc += o;
        }
        if (lane == 63) pw[wid] = sc;
        __syncthreads();
        if (t < 16) {
            int p = pw[t];
            int q = p;
#pragma unroll
            for (int off = 1; off < 16; off <<= 1) {
                int o = __shfl_up(q, off, 64);
                if (t >= off) q += o;
            }
            pw[t] = q - p;
        }
        __syncthreads();
        int ebase = pw[wid] + (sc - ts);
        if (i0 < NBKT) segc[i0] = ebase;
        if (i1 < NBKT) segc[i1] = ebase + v0;
        __syncthreads();
        for (int i = t; i < CHUNK / 4; i += 1024) {
            int4 d4 = *(const int4*)(ei + NE + cbeg + 4 * i);
            int4 s4 = *(const int4*)(ei + cbeg + 4 * i);
            float4 u4 = *(const float4*)(ea + cbeg + 4 * i);
            int dst[4] = {d4.x, d4.y, d4.z, d4.w};
            int src[4] = {s4.x, s4.y, s4.z, s4.w};
            float uu[4] = {u4.x, u4.y, u4.z, u4.w};
#pragma unroll
            for (int k = 0; k < 4; ++k) {
                int b = dst[k] >> BKT_SHIFT;
                int pos = atomicAdd(&segc[b], 1);
                sbuf[pos] = make_int2(src[k] | ((dst[k] & (BKT_NODES - 1)) << 17),
                                      __float_as_int(uu[k]));
            }
        }
        __syncthreads();
        for (int i = t; i < CHUNK; i += 1024) {
            int lo = 0, hi = NBKT - 1;
            while (lo < hi) {
                int mid = (lo + hi) >> 1;
                if (segc[mid] > i) hi = mid; else lo = mid + 1;
            }
            int b = lo;
            int start = b ? segc[b - 1] : 0;
            int p = gpos[b] + (i - start);
            int2 pk = sbuf[i];
            if (p < CAP_REG) {
                bkt[(size_t)b * CAP_REG + p] = pk;
            } else {
                int o = atomicAdd(novf, 1);
                if (o < OVF_MAX)
                    ovf[o] = make_int4(b * BKT_NODES + (((unsigned)pk.x) >> 17), pk.x & SRCM, pk.y, 0);
            }
        }
        __syncthreads();
        for (int b = t; b < NBKT; b += 1024) {
            int start = b ? segc[b - 1] : 0;
            gpos[b] += segc[b] - start;
        }
        __syncthreads();
    }
}

// ---- layer-1: register-staged single-pass sort; 4 lanes/node accumulate; persist sorted+segg ----
__global__ __launch_bounds__(256) void gather1_kernel(const int* __restrict__ gcur,
                                                      const int* __restrict__ novf,
                                                      const int4* __restrict__ ovf,
                                                      int2* __restrict__ bkt,
                                                      const unsigned* __restrict__ ab1p,
                                                      const float* __restrict__ r1,
                                                      unsigned short* __restrict__ h16,
                                                      float* __restrict__ dinv,
                                                      int* __restrict__ segg) {
    __shared__ int2 sorted[CAP_LDS];        // 9.5 KB
    __shared__ int cnt[BKT_NODES], cur[BKT_NODES], segb[BKT_NODES + 1];
    __shared__ float degsL[BKT_NODES];
    int t = threadIdx.x;
    int b = blockIdx.x;
    int tot = gcur[b];
    int beg = b * CAP_REG;
    if (t < BKT_NODES) { cnt[t] = 0; cur[t] = 0; degsL[t] = 0.f; }
    __syncthreads();
    int nodeBase = b * BKT_NODES;

    if (tot <= CAP_LDS) {
        int2 myE[5];
        int nE = 0;
        for (int e = t; e < tot; e += 256) {
            int2 pk = bkt[beg + e];
            myE[nE++] = pk;
            atomicAdd(&cnt[((unsigned)pk.x) >> 17], 1);
        }
        __syncthreads();
        if (t < BKT_NODES) {
            int v = cnt[t];
            int sc = v;
#pragma unroll
            for (int off = 1; off < 64; off <<= 1) {
                int o = __shfl_up(sc, off, 64);
                if (t >= off) sc += o;
            }
            segb[t] = sc - v;
            if (t == 63) segb[64] = sc;
        }
        __syncthreads();
        for (int k = 0; k < nE; ++k) {
            int loc = ((unsigned)myE[k].x) >> 17;
            int pos = segb[loc] + atomicAdd(&cur[loc], 1);
            sorted[pos] = myE[k];
        }
        __syncthreads();
        int nv = tot >> 1;
        int4* s4 = (int4*)sorted;
        int4* o4 = (int4*)(bkt + beg);
        for (int i = t; i < nv; i += 256) o4[i] = s4[i];
        if (t == 0 && (tot & 1)) bkt[beg + tot - 1] = sorted[tot - 1];
        if (t <= BKT_NODES) segg[b * (BKT_NODES + 1) + t] = segb[t];
        int node = t >> 2;
        int jq = t & 3;
        int s0 = segb[node], e2 = segb[node + 1];
        float acc[4] = {0.f, 0.f, 0.f, 0.f};
        int e = s0;
        for (; e + 3 < e2; e += 4) {
            int2 p0 = sorted[e];
            int2 p1 = sorted[e + 1];
            int2 p2 = sorted[e + 2];
            int2 p3 = sorted[e + 3];
            uint4 a0 = *(const uint4*)(ab1p + ((size_t)(p0.x & SRCM) << 4) + (jq << 2));
            uint4 a1 = *(const uint4*)(ab1p + ((size_t)(p1.x & SRCM) << 4) + (jq << 2));
            uint4 a2 = *(const uint4*)(ab1p + ((size_t)(p2.x & SRCM) << 4) + (jq << 2));
            uint4 a3 = *(const uint4*)(ab1p + ((size_t)(p3.x & SRCM) << 4) + (jq << 2));
            acc4(a0, __int_as_float(p0.y), acc);
            acc4(a1, __int_as_float(p1.y), acc);
            acc4(a2, __int_as_float(p2.y), acc);
            acc4(a3, __int_as_float(p3.y), acc);
        }
        for (; e < e2; ++e) {
            int2 pk = sorted[e];
            uint4 ap = *(const uint4*)(ab1p + ((size_t)(pk.x & SRCM) << 4) + (jq << 2));
            acc4(ap, __int_as_float(pk.y), acc);
        }
        int n = nodeBase + node;
        if (n < NN) {
            float d0 = 1.f / (float)max(e2 - s0, 1);
            float4 rv = *(const float4*)(r1 + ((size_t)n << 4) + (jq << 2));
            float rr[4] = {rv.x, rv.y, rv.z, rv.w};
            unsigned hw[4];
#pragma unroll
            for (int k = 0; k < 4; ++k) {
                float v = acc[k] * d0 + rr[k];
                hw[k] = bf16r(v > 0.f ? v : expm1f(v));
            }
            *(uint2*)(h16 + ((size_t)n << 4) + (jq << 2)) =
                make_uint2(hw[0] | (hw[1] << 16), hw[2] | (hw[3] << 16));
            if (jq == 0) dinv[n] = d0;
        }
    } else {
        // ---- legacy atomic path (statistically never) ----
        float* accL = (float*)sorted;
        int inreg = min(tot, CAP_REG);
        int end = beg + inreg;
        for (int i = t; i < BKT_NODES * HID; i += 256) accL[i] = 0.f;
        __syncthreads();
        int j = t & (HID - 1);
        int g = t >> 4;
        for (int e = beg + g; e < end; e += 16) {
            int2 pk = bkt[e];
            unsigned p = ab1p[(size_t)(pk.x & SRCM) * HID + j];
            atomicAdd(&accL[(((unsigned)pk.x) >> 17) * HID + j],
                      fmaf(__int_as_float(pk.y), bfd(p), bfa(p)));
            if (j == 0) atomicAdd(&degsL[((unsigned)pk.x) >> 17], 1.f);
        }
        int ovn = min(novf[0], OVF_MAX);
        for (int o = 0; o < ovn; ++o) {
            int4 ent = ovf[o];
            int loc = ent.x - nodeBase;
            if (loc >= 0 && loc < BKT_NODES && g == 0) {
                unsigned p = ab1p[(size_t)ent.y * HID + j];
                atomicAdd(&accL[loc * HID + j], fmaf(__int_as_float(ent.z), bfd(p), bfa(p)));
                if (j == 0) atomicAdd(&degsL[loc], 1.f);
            }
        }
        __syncthreads();
        if (t < BKT_NODES) degsL[t] = 1.f / fmaxf(degsL[t], 1.f);
        if (t == 0) segg[b * (BKT_NODES + 1)] = -1;
        __syncthreads();
        for (int idx = t; idx < BKT_NODES * HID; idx += 256) {
            int nl = idx >> 4, jj = idx & (HID - 1);
            int n = nodeBase + nl;
            if (n < NN) {
                float v = accL[idx] * degsL[nl] + r1[(size_t)n * HID + jj];
                h16[(size_t)n * HID + jj] = (unsigned short)bf16r(v > 0.f ? v : expm1f(v));
            }
        }
        if (t < BKT_NODES && nodeBase + t < NN) dinv[nodeBase + t] = degsL[t];
    }
}

// ---- layer-2: 6.4 KB LDS, register S0/S1, in-wave epilogue ----
#define HB_NODES 32
__global__ __launch_bounds__(256) void gather2_kernel(const int* __restrict__ gcur,
                                                      const int* __restrict__ novf,
                                                      const int4* __restrict__ ovf,
                                                      const int2* __restrict__ bkt,
                                                      const unsigned short* __restrict__ h16,
                                                      const float* __restrict__ W2,
                                                      const float* __restrict__ root2,
                                                      const float* __restrict__ bias2,
                                                      const float* __restrict__ dinv,
                                                      const int* __restrict__ segg,
                                                      float* __restrict__ out) {
    __shared__ float w20[HID * OUTF], w2d[HID * OUTF], wr[HID * OUTF];  // 6 KB
    __shared__ float bb[OUTF];
    __shared__ int segb[HB_NODES + 1];
    __shared__ int sflag;
    int t = threadIdx.x;
    int b2 = blockIdx.x;
    int b = b2 >> 1;
    int h = b2 & 1;
    for (int i = t; i < HID * OUTF; i += 256) {
        float a = W2[i];
        w20[i] = a;
        w2d[i] = W2[HID * OUTF + i] - a;
        wr[i] = root2[i];
    }
    if (t < OUTF) bb[t] = bias2[t];
    int tot = gcur[b];
    int beg = b * CAP_REG;
    int nodeBase = b * BKT_NODES + h * HB_NODES;
    if (t <= HB_NODES) segb[t] = segg[b * (BKT_NODES + 1) + h * HB_NODES + t];
    if (t == 0) sflag = segg[b * (BKT_NODES + 1)];
    __syncthreads();

    int node = t >> 3;
    int li = t & 7;
    int sub = li >> 1;
    int jh = li & 1;
    float S0[8] = {0.f, 0.f, 0.f, 0.f, 0.f, 0.f, 0.f, 0.f};
    float S1[8] = {0.f, 0.f, 0.f, 0.f, 0.f, 0.f, 0.f, 0.f};

    if (tot <= CAP_LDS && sflag != -1) {
        const int2* sp = bkt + beg;
        int s = segb[node], e2 = segb[node + 1];
        int e = s + sub;
        for (; e + 12 < e2; e += 16) {
            int2 p0 = sp[e];
            int2 p1 = sp[e + 4];
            int2 p2 = sp[e + 8];
            int2 p3 = sp[e + 12];
            uint4 h0 = *(const uint4*)(h16 + ((size_t)(p0.x & SRCM) << 4) + (jh << 3));
            uint4 h1 = *(const uint4*)(h16 + ((size_t)(p1.x & SRCM) << 4) + (jh << 3));
            uint4 h2 = *(const uint4*)(h16 + ((size_t)(p2.x & SRCM) << 4) + (jh << 3));
            uint4 h3 = *(const uint4*)(h16 + ((size_t)(p3.x & SRCM) << 4) + (jh << 3));
            acc8(h0, __int_as_float(p0.y), S0, S1);
            acc8(h1, __int_as_float(p1.y), S0, S1);
            acc8(h2, __int_as_float(p2.y), S0, S1);
            acc8(h3, __int_as_float(p3.y), S0, S1);
        }
        for (; e < e2; e += 4) {
            int2 pk = sp[e];
            uint4 hv = *(const uint4*)(h16 + ((size_t)(pk.x & SRCM) << 4) + (jh << 3));
            acc8(hv, __int_as_float(pk.y), S0, S1);
        }
#pragma unroll
        for (int k = 0; k < 8; ++k) {
            S0[k] += __shfl_xor(S0[k], 2); S0[k] += __shfl_xor(S0[k], 4);
            S1[k] += __shfl_xor(S1[k], 2); S1[k] += __shfl_xor(S1[k], 4);
        }
    } else {
        float* s0L = w20;
        float* s1L = w2d;
        for (int i = t; i < HB_NODES * HID; i += 256) { s0L[i] = 0.f; s1L[i] = 0.f; }
        __syncthreads();
        int j = t & (HID - 1);
        int g = t >> 4;
        int inreg = min(tot, CAP_REG);
        int end = beg + inreg;
        for (int e = beg + g; e < end; e += 16) {
            int2 pk = bkt[e];
            int loc = ((unsigned)pk.x) >> 17;
            if ((loc >> 5) == h) {
                float hvv = bfh(h16[(size_t)(pk.x & SRCM) * HID + j]);
                atomicAdd(&s0L[(loc & 31) * HID + j], hvv);
                atomicAdd(&s1L[(loc & 31) * HID + j], __int_as_float(pk.y) * hvv);
            }
        }
        int ovn = min(novf[0], OVF_MAX);
        for (int o = 0; o < ovn; ++o) {
            int4 ent = ovf[o];
            int loc = ent.x - nodeBase;
            if (loc >= 0 && loc < HB_NODES && g == 0) {
                float hvv = bfh(h16[(size_t)ent.y * HID + j]);
                atomicAdd(&s0L[loc * HID + j], hvv);
                atomicAdd(&s1L[loc * HID + j], __int_as_float(ent.z) * hvv);
            }
        }
        __syncthreads();
#pragma unroll
        for (int k = 0; k < 8; ++k) {
            S0[k] = s0L[node * HID + jh * 8 + k];
            S1[k] = s1L[node * HID + jh * 8 + k];
        }
        __syncthreads();
        for (int i = t; i < HID * OUTF; i += 256) {
            float a = W2[i];
            w20[i] = a;
            w2d[i] = W2[HID * OUTF + i] - a;
        }
        __syncthreads();
    }

    float F0[16], F1[16];
#pragma unroll
    for (int k = 0; k < 8; ++k) {
        float p0 = __shfl_xor(S0[k], 1);
        float p1 = __shfl_xor(S1[k], 1);
        F0[k] = jh ? p0 : S0[k];
        F0[8 + k] = jh ? S0[k] : p0;
        F1[k] = jh ? p1 : S1[k];
        F1[8 + k] = jh ? S1[k] : p1;
    }
    int n = nodeBase + node;
    if (n < NN) {
        float di = dinv[n];
        uint4 hA = *(const uint4*)(h16 + ((size_t)n << 4));
        uint4 hB = *(const uint4*)(h16 + ((size_t)n << 4) + 8);
        float hf[16];
        unsigned wa[4] = {hA.x, hA.y, hA.z, hA.w};
        unsigned wb[4] = {hB.x, hB.y, hB.z, hB.w};
#pragma unroll
        for (int q = 0; q < 4; ++q) {
            hf[2 * q]     = __uint_as_float(wa[q] << 16);
            hf[2 * q + 1] = __uint_as_float(wa[q] & 0xFFFF0000u);
            hf[8 + 2 * q]     = __uint_as_float(wb[q] << 16);
            hf[8 + 2 * q + 1] = __uint_as_float(wb[q] & 0xFFFF0000u);
        }
        float outv[4];
#pragma unroll
        for (int q = 0; q < 4; ++q) {
            int jj = li * 4 + q;
            float ms = 0.f;
#pragma unroll
            for (int f = 0; f < HID; ++f)
                ms += F0[f] * w20[f * OUTF + jj] + F1[f] * w2d[f * OUTF + jj];
            float v = ms * di + bb[jj];
#pragma unroll
            for (int f = 0; f < HID; ++f)
                v = fmaf(hf[f], wr[f * OUTF + jj], v);
            outv[q] = v;
        }
        float m = fmaxf(fmaxf(outv[0], outv[1]), fmaxf(outv[2], outv[3]));
        m = fmaxf(m, __shfl_xor(m, 1));
        m = fmaxf(m, __shfl_xor(m, 2));
        m = fmaxf(m, __shfl_xor(m, 4));
        float sl = expf(outv[0] - m) + expf(outv[1] - m) + expf(outv[2] - m) + expf(outv[3] - m);
        sl += __shfl_xor(sl, 1);
        sl += __shfl_xor(sl, 2);
        sl += __shfl_xor(sl, 4);
        float lse = m + logf(sl);
        *(float4*)(out + (size_t)n * OUTF + li * 4) =
            make_float4(outv[0] - lse, outv[1] - lse, outv[2] - lse, outv[3] - lse);
    }
}

extern "C" void kernel_launch(void* const* d_in, const int* in_sizes, int n_in,
                              void* d_out, int out_size, void* d_ws, size_t ws_size,
                              hipStream_t stream) {
    const float* x     = (const float*)d_in[0];
    const int*   ei    = (const int*)d_in[1];
    const float* ea    = (const float*)d_in[3];
    const float* W1    = (const float*)d_in[4];
    const float* root1 = (const float*)d_in[5];
    const float* bias1 = (const float*)d_in[6];
    const float* W2    = (const float*)d_in[7];
    const float* root2 = (const float*)d_in[8];
    const float* bias2 = (const float*)d_in[9];
    float* out = (float*)d_out;
    float* ws  = (float*)d_ws;

    const size_t N = NN;
    int*            gcur = (int*)(ws);                        // 1563
    int*            novf = (int*)(ws + 2000);                 // 1
    int4*           ovf  = (int4*)(ws + 2048);                // OVF_MAX int4
    float*          dinv = ws + 20000;                        // 100000
    int*            segg = (int*)(ws + 120000);               // NBKT*65 = 101595
    float*          r1   = ws + 222000;                       // 16N
    unsigned*       ab1p = (unsigned*)(ws + 222000 + 16 * N); // 16N u32
    unsigned short* h16  = (unsigned short*)(ws + 222000 + 32 * N); // 16N u16
    int2*           bkt  = (int2*)(ws + 222000 + 40 * N);     // NBKT*CAP_REG int2

    zeroG_kernel<<<(NBKT + 256) / 256, 256, 0, stream>>>(gcur, novf);
    fusedPP_kernel<<<PBLK3 + PROJ_BLKS, 1024, 0, stream>>>(ei, ea, gcur, novf, ovf, bkt,
                                                           x, W1, root1, bias1, ab1p, r1);
    gather1_kernel<<<NBKT, 256, 0, stream>>>(gcur, novf, ovf, bkt, ab1p, r1, h16, dinv, segg);
    gather2_kernel<<<NBKT * 2, 256, 0, stream>>>(gcur, novf, ovf, bkt, h16, W2, root2, bias2, dinv, segg, out);
}

// Round 20
// 111.480 us; speedup vs baseline: 1.1053x; 1.1053x over previous
//
#include <hip/hip_runtime.h>
#include <math.h>

#define NN 100000
#define NE 1600000
#define F_IN 64
#define HID 16
#define OUTF 32
#define BKT_SHIFT 6
#define BKT_NODES 64
#define NBKT 1563               // ceil(NN/64)
#define SRCM 0x1FFFF
#define CAP_REG 2048            // fixed region per bucket (mean 1024, sd 32)
#define CAP_LDS 1184            // fast-path LDS sort capacity (5 sigma; legacy covers rest)
#define PBLK3 200
#define EPB3 8000               // 200*8000 = 1.6M exact
#define CHUNK 2000              // 4 chunks per block
#define NCHK 4
#define OVF_MAX 4096

__device__ __forceinline__ unsigned bf16r(float f) {
    unsigned u = __float_as_uint(f);
    return (u + 0x7FFFu + ((u >> 16) & 1u)) >> 16;
}
__device__ __forceinline__ float bfa(unsigned p) { return __uint_as_float(p << 16); }
__device__ __forceinline__ float bfd(unsigned p) { return __uint_as_float(p & 0xFFFF0000u); }
__device__ __forceinline__ float bfh(unsigned short v) { return __uint_as_float(((unsigned)v) << 16); }

__device__ __forceinline__ void acc8(uint4 hv, float u, float* s0, float* s1) {
    unsigned w[4] = {hv.x, hv.y, hv.z, hv.w};
#pragma unroll
    for (int q = 0; q < 4; ++q) {
        float lo = __uint_as_float(w[q] << 16);
        float hi = __uint_as_float(w[q] & 0xFFFF0000u);
        s0[2 * q]     += lo; s1[2 * q]     = fmaf(u, lo, s1[2 * q]);
        s0[2 * q + 1] += hi; s1[2 * q + 1] = fmaf(u, hi, s1[2 * q + 1]);
    }
}
__device__ __forceinline__ void acc4(uint4 ap, float u, float* a) {
    unsigned w[4] = {ap.x, ap.y, ap.z, ap.w};
#pragma unroll
    for (int q = 0; q < 4; ++q)
        a[q] += fmaf(u, bfd(w[q]), bfa(w[q]));
}

// ---- fused partition v3: block-level claim + chunked LDS-sort + L2-accumulating writeout ----
__global__ __launch_bounds__(1024) void partF_kernel(const int* __restrict__ ei,
                                                     const float* __restrict__ ea,
                                                     int* __restrict__ gcur,
                                                     int* __restrict__ novf,
                                                     int4* __restrict__ ovf,
                                                     int2* __restrict__ bkt) {
    __shared__ int gpos[NBKT];      // counts -> claimed global next-position per bucket
    __shared__ int segc[NBKT];      // per-chunk: hist -> excl-scan -> cursor -> ends
    __shared__ int pw[16];
    __shared__ int2 sbuf[CHUNK];    // 16 KB bucket-sorted chunk payloads
    int t = threadIdx.x, blk = blockIdx.x;
    for (int i = t; i < NBKT; i += 1024) gpos[i] = 0;
    __syncthreads();
    int beg = blk * EPB3;
    // block-level hist (dst pass 1)
    for (int i = t; i < EPB3 / 4; i += 1024) {
        int4 d4 = *(const int4*)(ei + NE + beg + 4 * i);
        atomicAdd(&gpos[d4.x >> BKT_SHIFT], 1);
        atomicAdd(&gpos[d4.y >> BKT_SHIFT], 1);
        atomicAdd(&gpos[d4.z >> BKT_SHIFT], 1);
        atomicAdd(&gpos[d4.w >> BKT_SHIFT], 1);
    }
    __syncthreads();
    // single claim per block -> contiguous slice per bucket
    int rot = (blk * 397) % NBKT;
    for (int k = t; k < NBKT; k += 1024) {
        int i = k + rot; if (i >= NBKT) i -= NBKT;
        int c = gpos[i];
        gpos[i] = c ? atomicAdd(&gcur[i], c) : 0;
    }
    __syncthreads();
    for (int c = 0; c < NCHK; ++c) {
        int cbeg = beg + c * CHUNK;
        for (int i = t; i < NBKT; i += 1024) segc[i] = 0;
        __syncthreads();
        // chunk hist (dst pass 2)
        for (int i = t; i < CHUNK / 4; i += 1024) {
            int4 d4 = *(const int4*)(ei + NE + cbeg + 4 * i);
            atomicAdd(&segc[d4.x >> BKT_SHIFT], 1);
            atomicAdd(&segc[d4.y >> BKT_SHIFT], 1);
            atomicAdd(&segc[d4.z >> BKT_SHIFT], 1);
            atomicAdd(&segc[d4.w >> BKT_SHIFT], 1);
        }
        __syncthreads();
        // in-place exclusive scan of segc
        int i0 = 2 * t, i1 = 2 * t + 1;
        int v0 = (i0 < NBKT) ? segc[i0] : 0;
        int v1 = (i1 < NBKT) ? segc[i1] : 0;
        int ts = v0 + v1;
        int lane = t & 63, wid = t >> 6;
        int sc = ts;
#pragma unroll
        for (int off = 1; off < 64; off <<= 1) {
            int o = __shfl_up(sc, off, 64);
            if (lane >= off) sc += o;
        }
        if (lane == 63) pw[wid] = sc;
        __syncthreads();
        if (t < 16) {
            int p = pw[t];
            int q = p;
#pragma unroll
            for (int off = 1; off < 16; off <<= 1) {
                int o = __shfl_up(q, off, 64);
                if (t >= off) q += o;
            }
            pw[t] = q - p;  // exclusive
        }
        __syncthreads();
        int ebase = pw[wid] + (sc - ts);
        if (i0 < NBKT) segc[i0] = ebase;
        if (i1 < NBKT) segc[i1] = ebase + v0;
        __syncthreads();
        // stage chunk bucket-sorted into sbuf (segc acts as cursor)
        for (int i = t; i < CHUNK / 4; i += 1024) {
            int4 d4 = *(const int4*)(ei + NE + cbeg + 4 * i);
            int4 s4 = *(const int4*)(ei + cbeg + 4 * i);
            float4 u4 = *(const float4*)(ea + cbeg + 4 * i);
            int dst[4] = {d4.x, d4.y, d4.z, d4.w};
            int src[4] = {s4.x, s4.y, s4.z, s4.w};
            float uu[4] = {u4.x, u4.y, u4.z, u4.w};
#pragma unroll
            for (int k = 0; k < 4; ++k) {
                int b = dst[k] >> BKT_SHIFT;
                int pos = atomicAdd(&segc[b], 1);
                sbuf[pos] = make_int2(src[k] | ((dst[k] & (BKT_NODES - 1)) << 17),
                                      __float_as_int(uu[k]));
            }
        }
        __syncthreads();  // segc now holds inclusive ends (monotone)
        // writeout: bucket via binary search on ends; append to block's slice
        for (int i = t; i < CHUNK; i += 1024) {
            int lo = 0, hi = NBKT - 1;
            while (lo < hi) {
                int mid = (lo + hi) >> 1;
                if (segc[mid] > i) hi = mid; else lo = mid + 1;
            }
            int b = lo;
            int start = b ? segc[b - 1] : 0;
            int p = gpos[b] + (i - start);
            int2 pk = sbuf[i];
            if (p < CAP_REG) {
                bkt[(size_t)b * CAP_REG + p] = pk;
            } else {
                int o = atomicAdd(novf, 1);
                if (o < OVF_MAX)
                    ovf[o] = make_int4(b * BKT_NODES + (((unsigned)pk.x) >> 17), pk.x & SRCM, pk.y, 0);
            }
        }
        __syncthreads();
        // advance gpos by this chunk's per-bucket counts
        for (int b = t; b < NBKT; b += 1024) {
            int start = b ? segc[b - 1] : 0;
            gpos[b] += segc[b] - start;
        }
        __syncthreads();
    }
}

// ---- layer-1 projection + gcur/novf zeroing (runs before partF) ----
__global__ __launch_bounds__(256) void proj1z_kernel(const float* __restrict__ x,
                                                     const float* __restrict__ W1,
                                                     const float* __restrict__ root1,
                                                     const float* __restrict__ bias1,
                                                     unsigned* __restrict__ ab1p,
                                                     float* __restrict__ r1,
                                                     int* __restrict__ gcur,
                                                     int* __restrict__ novf) {
    int gz = blockIdx.x * 256 + threadIdx.x;
    if (gz < NBKT) gcur[gz] = 0;
    if (gz == NBKT) novf[0] = 0;
    __shared__ float w[2 * F_IN * HID];
    __shared__ float wr[F_IN * HID];
    __shared__ float bb[HID];
    for (int i = threadIdx.x; i < 2 * F_IN * HID; i += 256) w[i] = W1[i];
    for (int i = threadIdx.x; i < F_IN * HID; i += 256) wr[i] = root1[i];
    if (threadIdx.x < HID) bb[threadIdx.x] = bias1[threadIdx.x];
    __syncthreads();
    int n = blockIdx.x * 256 + threadIdx.x;
    if (n >= NN) return;
    float accA[HID], accB[HID], accR[HID];
#pragma unroll
    for (int o = 0; o < HID; ++o) { accA[o] = 0.f; accB[o] = 0.f; accR[o] = bb[o]; }
    const float4* xr4 = (const float4*)(x + (size_t)n * F_IN);
    for (int f4 = 0; f4 < F_IN / 4; ++f4) {
        float4 xv4 = xr4[f4];
        float xs[4] = {xv4.x, xv4.y, xv4.z, xv4.w};
#pragma unroll
        for (int q = 0; q < 4; ++q) {
            int f = f4 * 4 + q;
            float xv = xs[q];
            const float* w0 = &w[f * HID];
            const float* w1 = &w[F_IN * HID + f * HID];
            const float* w2 = &wr[f * HID];
#pragma unroll
            for (int o = 0; o < HID; ++o) {
                accA[o] = fmaf(xv, w0[o], accA[o]);
                accB[o] = fmaf(xv, w1[o], accB[o]);
                accR[o] = fmaf(xv, w2[o], accR[o]);
            }
        }
    }
    unsigned* ar = ab1p + (size_t)n * HID;
    float* rr = r1 + (size_t)n * HID;
#pragma unroll
    for (int o = 0; o < HID; ++o) {
        ar[o] = bf16r(accA[o]) | (bf16r(accB[o] - accA[o]) << 16);
        rr[o] = accR[o];
    }
}

// ---- layer-1: register-staged single-pass sort; 4 lanes/node accumulate; persist sorted+segg ----
__global__ __launch_bounds__(256) void gather1_kernel(const int* __restrict__ gcur,
                                                      const int* __restrict__ novf,
                                                      const int4* __restrict__ ovf,
                                                      int2* __restrict__ bkt,
                                                      const unsigned* __restrict__ ab1p,
                                                      const float* __restrict__ r1,
                                                      unsigned short* __restrict__ h16,
                                                      float* __restrict__ dinv,
                                                      int* __restrict__ segg) {
    __shared__ int2 sorted[CAP_LDS];        // 9.5 KB
    __shared__ int cnt[BKT_NODES], cur[BKT_NODES], segb[BKT_NODES + 1];
    __shared__ float degsL[BKT_NODES];
    int t = threadIdx.x;
    int b = blockIdx.x;
    int tot = gcur[b];
    int beg = b * CAP_REG;
    if (t < BKT_NODES) { cnt[t] = 0; cur[t] = 0; degsL[t] = 0.f; }
    __syncthreads();
    int nodeBase = b * BKT_NODES;

    if (tot <= CAP_LDS) {
        // single global read: stage payloads in registers, count from registers
        int2 myE[5];
        int nE = 0;
        for (int e = t; e < tot; e += 256) {
            int2 pk = bkt[beg + e];
            myE[nE++] = pk;
            atomicAdd(&cnt[((unsigned)pk.x) >> 17], 1);
        }
        __syncthreads();
        if (t < BKT_NODES) {
            int v = cnt[t];
            int sc = v;
#pragma unroll
            for (int off = 1; off < 64; off <<= 1) {
                int o = __shfl_up(sc, off, 64);
                if (t >= off) sc += o;
            }
            segb[t] = sc - v;
            if (t == 63) segb[64] = sc;
        }
        __syncthreads();
        // scatter from registers into loc-sorted LDS
        for (int k = 0; k < nE; ++k) {
            int loc = ((unsigned)myE[k].x) >> 17;
            int pos = segb[loc] + atomicAdd(&cur[loc], 1);
            sorted[pos] = myE[k];
        }
        __syncthreads();
        // persist sorted order + segment bounds for gather2 (vectorized)
        int nv = tot >> 1;
        int4* s4 = (int4*)sorted;
        int4* o4 = (int4*)(bkt + beg);
        for (int i = t; i < nv; i += 256) o4[i] = s4[i];
        if (t == 0 && (tot & 1)) bkt[beg + tot - 1] = sorted[tot - 1];
        if (t <= BKT_NODES) segg[b * (BKT_NODES + 1) + t] = segb[t];
        int node = t >> 2;
        int jq = t & 3;
        int s0 = segb[node], e2 = segb[node + 1];
        float acc[4] = {0.f, 0.f, 0.f, 0.f};
        int e = s0;
        for (; e + 3 < e2; e += 4) {
            int2 p0 = sorted[e];
            int2 p1 = sorted[e + 1];
            int2 p2 = sorted[e + 2];
            int2 p3 = sorted[e + 3];
            uint4 a0 = *(const uint4*)(ab1p + ((size_t)(p0.x & SRCM) << 4) + (jq << 2));
            uint4 a1 = *(const uint4*)(ab1p + ((size_t)(p1.x & SRCM) << 4) + (jq << 2));
            uint4 a2 = *(const uint4*)(ab1p + ((size_t)(p2.x & SRCM) << 4) + (jq << 2));
            uint4 a3 = *(const uint4*)(ab1p + ((size_t)(p3.x & SRCM) << 4) + (jq << 2));
            acc4(a0, __int_as_float(p0.y), acc);
            acc4(a1, __int_as_float(p1.y), acc);
            acc4(a2, __int_as_float(p2.y), acc);
            acc4(a3, __int_as_float(p3.y), acc);
        }
        for (; e < e2; ++e) {
            int2 pk = sorted[e];
            uint4 ap = *(const uint4*)(ab1p + ((size_t)(pk.x & SRCM) << 4) + (jq << 2));
            acc4(ap, __int_as_float(pk.y), acc);
        }
        int n = nodeBase + node;
        if (n < NN) {
            float d0 = 1.f / (float)max(e2 - s0, 1);
            float4 rv = *(const float4*)(r1 + ((size_t)n << 4) + (jq << 2));
            float rr[4] = {rv.x, rv.y, rv.z, rv.w};
            unsigned hw[4];
#pragma unroll
            for (int k = 0; k < 4; ++k) {
                float v = acc[k] * d0 + rr[k];
                hw[k] = bf16r(v > 0.f ? v : expm1f(v));
            }
            *(uint2*)(h16 + ((size_t)n << 4) + (jq << 2)) =
                make_uint2(hw[0] | (hw[1] << 16), hw[2] | (hw[3] << 16));
            if (jq == 0) dinv[n] = d0;
        }
    } else {
        // ---- legacy atomic path (statistically never) ----
        float* accL = (float*)sorted;
        int inreg = min(tot, CAP_REG);
        int end = beg + inreg;
        for (int i = t; i < BKT_NODES * HID; i += 256) accL[i] = 0.f;
        __syncthreads();
        int j = t & (HID - 1);
        int g = t >> 4;
        for (int e = beg + g; e < end; e += 16) {
            int2 pk = bkt[e];
            unsigned p = ab1p[(size_t)(pk.x & SRCM) * HID + j];
            atomicAdd(&accL[(((unsigned)pk.x) >> 17) * HID + j],
                      fmaf(__int_as_float(pk.y), bfd(p), bfa(p)));
            if (j == 0) atomicAdd(&degsL[((unsigned)pk.x) >> 17], 1.f);
        }
        int ovn = min(novf[0], OVF_MAX);
        for (int o = 0; o < ovn; ++o) {
            int4 ent = ovf[o];
            int loc = ent.x - nodeBase;
            if (loc >= 0 && loc < BKT_NODES && g == 0) {
                unsigned p = ab1p[(size_t)ent.y * HID + j];
                atomicAdd(&accL[loc * HID + j], fmaf(__int_as_float(ent.z), bfd(p), bfa(p)));
                if (j == 0) atomicAdd(&degsL[loc], 1.f);
            }
        }
        __syncthreads();
        if (t < BKT_NODES) degsL[t] = 1.f / fmaxf(degsL[t], 1.f);
        if (t == 0) segg[b * (BKT_NODES + 1)] = -1;
        __syncthreads();
        for (int idx = t; idx < BKT_NODES * HID; idx += 256) {
            int nl = idx >> 4, jj = idx & (HID - 1);
            int n = nodeBase + nl;
            if (n < NN) {
                float v = accL[idx] * degsL[nl] + r1[(size_t)n * HID + jj];
                h16[(size_t)n * HID + jj] = (unsigned short)bf16r(v > 0.f ? v : expm1f(v));
            }
        }
        if (t < BKT_NODES && nodeBase + t < NN) dinv[nodeBase + t] = degsL[t];
    }
}

// ---- layer-2: 6.4 KB LDS, register S0/S1, in-wave epilogue ----
#define HB_NODES 32
__global__ __launch_bounds__(256) void gather2_kernel(const int* __restrict__ gcur,
                                                      const int* __restrict__ novf,
                                                      const int4* __restrict__ ovf,
                                                      const int2* __restrict__ bkt,
                                                      const unsigned short* __restrict__ h16,
                                                      const float* __restrict__ W2,
                                                      const float* __restrict__ root2,
                                                      const float* __restrict__ bias2,
                                                      const float* __restrict__ dinv,
                                                      const int* __restrict__ segg,
                                                      float* __restrict__ out) {
    __shared__ float w20[HID * OUTF], w2d[HID * OUTF], wr[HID * OUTF];  // 6 KB
    __shared__ float bb[OUTF];
    __shared__ int segb[HB_NODES + 1];
    __shared__ int sflag;
    int t = threadIdx.x;
    int b2 = blockIdx.x;
    int b = b2 >> 1;
    int h = b2 & 1;
    for (int i = t; i < HID * OUTF; i += 256) {
        float a = W2[i];
        w20[i] = a;
        w2d[i] = W2[HID * OUTF + i] - a;
        wr[i] = root2[i];
    }
    if (t < OUTF) bb[t] = bias2[t];
    int tot = gcur[b];
    int beg = b * CAP_REG;
    int nodeBase = b * BKT_NODES + h * HB_NODES;
    if (t <= HB_NODES) segb[t] = segg[b * (BKT_NODES + 1) + h * HB_NODES + t];
    if (t == 0) sflag = segg[b * (BKT_NODES + 1)];
    __syncthreads();

    int node = t >> 3;
    int li = t & 7;
    int sub = li >> 1;
    int jh = li & 1;
    float S0[8] = {0.f, 0.f, 0.f, 0.f, 0.f, 0.f, 0.f, 0.f};
    float S1[8] = {0.f, 0.f, 0.f, 0.f, 0.f, 0.f, 0.f, 0.f};

    if (tot <= CAP_LDS && sflag != -1) {
        const int2* sp = bkt + beg;
        int s = segb[node], e2 = segb[node + 1];
        int e = s + sub;
        for (; e + 12 < e2; e += 16) {
            int2 p0 = sp[e];
            int2 p1 = sp[e + 4];
            int2 p2 = sp[e + 8];
            int2 p3 = sp[e + 12];
            uint4 h0 = *(const uint4*)(h16 + ((size_t)(p0.x & SRCM) << 4) + (jh << 3));
            uint4 h1 = *(const uint4*)(h16 + ((size_t)(p1.x & SRCM) << 4) + (jh << 3));
            uint4 h2 = *(const uint4*)(h16 + ((size_t)(p2.x & SRCM) << 4) + (jh << 3));
            uint4 h3 = *(const uint4*)(h16 + ((size_t)(p3.x & SRCM) << 4) + (jh << 3));
            acc8(h0, __int_as_float(p0.y), S0, S1);
            acc8(h1, __int_as_float(p1.y), S0, S1);
            acc8(h2, __int_as_float(p2.y), S0, S1);
            acc8(h3, __int_as_float(p3.y), S0, S1);
        }
        for (; e < e2; e += 4) {
            int2 pk = sp[e];
            uint4 hv = *(const uint4*)(h16 + ((size_t)(pk.x & SRCM) << 4) + (jh << 3));
            acc8(hv, __int_as_float(pk.y), S0, S1);
        }
#pragma unroll
        for (int k = 0; k < 8; ++k) {
            S0[k] += __shfl_xor(S0[k], 2); S0[k] += __shfl_xor(S0[k], 4);
            S1[k] += __shfl_xor(S1[k], 2); S1[k] += __shfl_xor(S1[k], 4);
        }
    } else {
        float* s0L = w20;
        float* s1L = w2d;
        for (int i = t; i < HB_NODES * HID; i += 256) { s0L[i] = 0.f; s1L[i] = 0.f; }
        __syncthreads();
        int j = t & (HID - 1);
        int g = t >> 4;
        int inreg = min(tot, CAP_REG);
        int end = beg + inreg;
        for (int e = beg + g; e < end; e += 16) {
            int2 pk = bkt[e];
            int loc = ((unsigned)pk.x) >> 17;
            if ((loc >> 5) == h) {
                float hvv = bfh(h16[(size_t)(pk.x & SRCM) * HID + j]);
                atomicAdd(&s0L[(loc & 31) * HID + j], hvv);
                atomicAdd(&s1L[(loc & 31) * HID + j], __int_as_float(pk.y) * hvv);
            }
        }
        int ovn = min(novf[0], OVF_MAX);
        for (int o = 0; o < ovn; ++o) {
            int4 ent = ovf[o];
            int loc = ent.x - nodeBase;
            if (loc >= 0 && loc < HB_NODES && g == 0) {
                float hvv = bfh(h16[(size_t)ent.y * HID + j]);
                atomicAdd(&s0L[loc * HID + j], hvv);
                atomicAdd(&s1L[loc * HID + j], __int_as_float(ent.z) * hvv);
            }
        }
        __syncthreads();
#pragma unroll
        for (int k = 0; k < 8; ++k) {
            S0[k] = s0L[node * HID + jh * 8 + k];
            S1[k] = s1L[node * HID + jh * 8 + k];
        }
        __syncthreads();
        for (int i = t; i < HID * OUTF; i += 256) {
            float a = W2[i];
            w20[i] = a;
            w2d[i] = W2[HID * OUTF + i] - a;
        }
        __syncthreads();
    }

    float F0[16], F1[16];
#pragma unroll
    for (int k = 0; k < 8; ++k) {
        float p0 = __shfl_xor(S0[k], 1);
        float p1 = __shfl_xor(S1[k], 1);
        F0[k] = jh ? p0 : S0[k];
        F0[8 + k] = jh ? S0[k] : p0;
        F1[k] = jh ? p1 : S1[k];
        F1[8 + k] = jh ? S1[k] : p1;
    }
    int n = nodeBase + node;
    if (n < NN) {
        float di = dinv[n];
        uint4 hA = *(const uint4*)(h16 + ((size_t)n << 4));
        uint4 hB = *(const uint4*)(h16 + ((size_t)n << 4) + 8);
        float hf[16];
        unsigned wa[4] = {hA.x, hA.y, hA.z, hA.w};
        unsigned wb[4] = {hB.x, hB.y, hB.z, hB.w};
#pragma unroll
        for (int q = 0; q < 4; ++q) {
            hf[2 * q]     = __uint_as_float(wa[q] << 16);
            hf[2 * q + 1] = __uint_as_float(wa[q] & 0xFFFF0000u);
            hf[8 + 2 * q]     = __uint_as_float(wb[q] << 16);
            hf[8 + 2 * q + 1] = __uint_as_float(wb[q] & 0xFFFF0000u);
        }
        float outv[4];
#pragma unroll
        for (int q = 0; q < 4; ++q) {
            int jj = li * 4 + q;
            float ms = 0.f;
#pragma unroll
            for (int f = 0; f < HID; ++f)
                ms += F0[f] * w20[f * OUTF + jj] + F1[f] * w2d[f * OUTF + jj];
            float v = ms * di + bb[jj];
#pragma unroll
            for (int f = 0; f < HID; ++f)
                v = fmaf(hf[f], wr[f * OUTF + jj], v);
            outv[q] = v;
        }
        float m = fmaxf(fmaxf(outv[0], outv[1]), fmaxf(outv[2], outv[3]));
        m = fmaxf(m, __shfl_xor(m, 1));
        m = fmaxf(m, __shfl_xor(m, 2));
        m = fmaxf(m, __shfl_xor(m, 4));
        float sl = expf(outv[0] - m) + expf(outv[1] - m) + expf(outv[2] - m) + expf(outv[3] - m);
        sl += __shfl_xor(sl, 1);
        sl += __shfl_xor(sl, 2);
        sl += __shfl_xor(sl, 4);
        float lse = m + logf(sl);
        *(float4*)(out + (size_t)n * OUTF + li * 4) =
            make_float4(outv[0] - lse, outv[1] - lse, outv[2] - lse, outv[3] - lse);
    }
}

extern "C" void kernel_launch(void* const* d_in, const int* in_sizes, int n_in,
                              void* d_out, int out_size, void* d_ws, size_t ws_size,
                              hipStream_t stream) {
    const float* x     = (const float*)d_in[0];
    const int*   ei    = (const int*)d_in[1];
    const float* ea    = (const float*)d_in[3];
    const float* W1    = (const float*)d_in[4];
    const float* root1 = (const float*)d_in[5];
    const float* bias1 = (const float*)d_in[6];
    const float* W2    = (const float*)d_in[7];
    const float* root2 = (const float*)d_in[8];
    const float* bias2 = (const float*)d_in[9];
    float* out = (float*)d_out;
    float* ws  = (float*)d_ws;

    const size_t N = NN;
    int*            gcur = (int*)(ws);                        // 1563
    int*            novf = (int*)(ws + 2000);                 // 1
    int4*           ovf  = (int4*)(ws + 2048);                // OVF_MAX int4
    float*          dinv = ws + 20000;                        // 100000
    int*            segg = (int*)(ws + 120000);               // NBKT*65 = 101595
    float*          r1   = ws + 222000;                       // 16N
    unsigned*       ab1p = (unsigned*)(ws + 222000 + 16 * N); // 16N u32
    unsigned short* h16  = (unsigned short*)(ws + 222000 + 32 * N); // 16N u16
    int2*           bkt  = (int2*)(ws + 222000 + 40 * N);     // NBKT*CAP_REG int2

    int nbN = (NN + 255) / 256;
    proj1z_kernel<<<nbN, 256, 0, stream>>>(x, W1, root1, bias1, ab1p, r1, gcur, novf);
    partF_kernel<<<PBLK3, 1024, 0, stream>>>(ei, ea, gcur, novf, ovf, bkt);
    gather1_kernel<<<NBKT, 256, 0, stream>>>(gcur, novf, ovf, bkt, ab1p, r1, h16, dinv, segg);
    gather2_kernel<<<NBKT * 2, 256, 0, stream>>>(gcur, novf, ovf, bkt, h16, W2, root2, bias2, dinv, segg, out);
}